// Round 6
// baseline (42.371 us; speedup 1.0000x reference)
//
#include <hip/hip_runtime.h>
#include <math.h>

#define HDIM 2048
#define NEXP 8
#define TB 4                          // tokens per wave
#define BLOCK 512
#define WAVES_PB 8
#define TOK_PB (WAVES_PB * TB)        // 32 tokens per block
#define CH 256                        // floats of H per chunk per wave
#define NCH (HDIM / CH)               // 8 chunks

// ---------------------------------------------------------------------------
// R6: W lives in LDS. Every previous round paid 268 MB of chip-wide global
// re-reads of the same 64 KB W (L1 thrashed by the x stream -> hot L2 banks).
// Now: one cooperative 64 KB W->LDS stage per block, then the main loop's
// only global traffic is the pure coalesced x stream; W comes from
// ds_read_b128. 512-thr blocks, 64KB LDS -> 2 blocks/CU = 16 waves/CU.
// acc[32] = 4 tokens x 8 experts/lane; shuffle-fold -> top-2 -> softmax;
// histogram via LDS counts + 8 float atomics/block (integer-valued float
// adds < 2^24 are exact -> deterministic).
// ---------------------------------------------------------------------------
__global__ __launch_bounds__(BLOCK, 4) void
router_main(const float* __restrict__ x,
            const float* __restrict__ W,
            float* __restrict__ out_scores,   // [T,2]
            float* __restrict__ out_idx,      // [T,2] as float
            float* __restrict__ hist,         // [8], pre-zeroed
            int T)
{
    __shared__ float wlds[NEXP][HDIM];        // 64 KB
    __shared__ int cnt[NEXP];

    // ---- cooperative W -> LDS stage (coalesced, 8 float4 per thread) ----
    {
        const float4* __restrict__ Wv = reinterpret_cast<const float4*>(W);
        float4* wl = reinterpret_cast<float4*>(&wlds[0][0]);
#pragma unroll
        for (int j = 0; j < (NEXP * HDIM / 4) / BLOCK; ++j)
            wl[threadIdx.x + j * BLOCK] = Wv[threadIdx.x + j * BLOCK];
    }
    if (threadIdx.x < NEXP) cnt[threadIdx.x] = 0;
    __syncthreads();

    const int lane = threadIdx.x & 63;
    const int wv   = threadIdx.x >> 6;
    const int tok0 = blockIdx.x * TOK_PB + wv * TB;

    const float* xb[TB];
#pragma unroll
    for (int t = 0; t < TB; ++t) {
        int tt = tok0 + t; if (tt > T - 1) tt = T - 1;
        xb[t] = x + (size_t)tt * HDIM + lane * 4;
    }

    float acc[TB * NEXP];
#pragma unroll
    for (int i = 0; i < TB * NEXP; ++i) acc[i] = 0.f;

    // ---- main loop: global traffic = x stream only; W from LDS ----
#pragma unroll
    for (int c = 0; c < NCH; ++c) {
        const int h = c * CH + lane * 4;
        float4 xv[TB];
#pragma unroll
        for (int t = 0; t < TB; ++t)
            xv[t] = *reinterpret_cast<const float4*>(xb[t] + c * CH);

#pragma unroll
        for (int half = 0; half < 2; ++half) {
            const int b = half * 4;
            float4 w0 = *reinterpret_cast<const float4*>(&wlds[b + 0][h]);
            float4 w1 = *reinterpret_cast<const float4*>(&wlds[b + 1][h]);
            float4 w2 = *reinterpret_cast<const float4*>(&wlds[b + 2][h]);
            float4 w3 = *reinterpret_cast<const float4*>(&wlds[b + 3][h]);
#pragma unroll
            for (int t = 0; t < TB; ++t) {
                float a0 = acc[t * NEXP + b + 0];
                float a1 = acc[t * NEXP + b + 1];
                float a2 = acc[t * NEXP + b + 2];
                float a3 = acc[t * NEXP + b + 3];
                a0 = fmaf(xv[t].x, w0.x, a0); a0 = fmaf(xv[t].y, w0.y, a0);
                a0 = fmaf(xv[t].z, w0.z, a0); a0 = fmaf(xv[t].w, w0.w, a0);
                a1 = fmaf(xv[t].x, w1.x, a1); a1 = fmaf(xv[t].y, w1.y, a1);
                a1 = fmaf(xv[t].z, w1.z, a1); a1 = fmaf(xv[t].w, w1.w, a1);
                a2 = fmaf(xv[t].x, w2.x, a2); a2 = fmaf(xv[t].y, w2.y, a2);
                a2 = fmaf(xv[t].z, w2.z, a2); a2 = fmaf(xv[t].w, w2.w, a2);
                a3 = fmaf(xv[t].x, w3.x, a3); a3 = fmaf(xv[t].y, w3.y, a3);
                a3 = fmaf(xv[t].z, w3.z, a3); a3 = fmaf(xv[t].w, w3.w, a3);
                acc[t * NEXP + b + 0] = a0;
                acc[t * NEXP + b + 1] = a1;
                acc[t * NEXP + b + 2] = a2;
                acc[t * NEXP + b + 3] = a3;
            }
        }
    }

    // ---- reduce 32 partial sums across 64 lanes (R1-verified fold) ----
#pragma unroll
    for (int j = 0; j < 32; ++j) acc[j] += __shfl_xor(acc[j], 32, 64);

#define FOLD(SM)                                                          \
    {                                                                     \
        const bool up = (lane & SM) != 0;                                 \
        _Pragma("unroll")                                                 \
        for (int j = 0; j < SM; ++j) {                                    \
            float keep = up ? acc[j + SM] : acc[j];                       \
            float send = up ? acc[j] : acc[j + SM];                       \
            acc[j] = keep + __shfl_xor(send, SM, 64);                     \
        }                                                                 \
    }
    FOLD(16) FOLD(8) FOLD(4) FOLD(2) FOLD(1)
#undef FOLD

    // lane l holds logit(token tok0 + ((l&31)>>3), expert l&7)
    const int e_my  = lane & 7;
    const int t_loc = (lane & 31) >> 3;
    const float mylg = acc[0];

    // ---- top-1 within each aligned 8-lane group (tie -> lower index) ----
    float v1 = mylg;
    int   i1 = e_my;
#pragma unroll
    for (int m = 1; m <= 4; m <<= 1) {
        float ov = __shfl_xor(v1, m, 64);
        int   oi = __shfl_xor(i1, m, 64);
        if (ov > v1 || (ov == v1 && oi < i1)) { v1 = ov; i1 = oi; }
    }
    // ---- top-2: exclude i1, repeat ----
    float v2 = (e_my == i1) ? -3.402823466e+38f : mylg;
    int   i2 = e_my;
#pragma unroll
    for (int m = 1; m <= 4; m <<= 1) {
        float ov = __shfl_xor(v2, m, 64);
        int   oi = __shfl_xor(i2, m, 64);
        if (ov > v2 || (ov == v2 && oi < i2)) { v2 = ov; i2 = oi; }
    }

    // ---- softmax over the 2 selected logits (fp32, stable: v1 >= v2) ----
    const float ed  = expf(v2 - v1);
    const float inv = 1.0f / (1.0f + ed);

    const int tok = tok0 + t_loc;
    if (lane < 32 && e_my == 0 && tok < T) {
        *reinterpret_cast<float2*>(out_scores + 2 * tok) = make_float2(inv, ed * inv);
        *reinterpret_cast<float2*>(out_idx    + 2 * tok) = make_float2((float)i1, (float)i2);
        atomicAdd(&cnt[i1], 1);
        atomicAdd(&cnt[i2], 1);
    }

    __syncthreads();
    if (threadIdx.x < NEXP)
        atomicAdd(&hist[threadIdx.x], (float)cnt[threadIdx.x]);
}

extern "C" void kernel_launch(void* const* d_in, const int* in_sizes, int n_in,
                              void* d_out, int out_size, void* d_ws, size_t ws_size,
                              hipStream_t stream)
{
    const float* x = (const float*)d_in[0];
    const float* W = (const float*)d_in[1];
    const int T = in_sizes[0] / HDIM;          // 16384

    float* out        = (float*)d_out;
    float* out_scores = out;                   // [T,2]
    float* out_idx    = out + (size_t)2 * T;   // [T,2]
    float* hist       = out + (size_t)4 * T;   // [8]

    // zero the 8 hist slots every call (atomics accumulate into them)
    hipMemsetAsync(hist, 0, NEXP * sizeof(float), stream);

    const int nblocks = (T + TOK_PB - 1) / TOK_PB;   // 512
    router_main<<<nblocks, BLOCK, 0, stream>>>(x, W, out_scores, out_idx, hist, T);
}